// Round 20
// baseline (144.988 us; speedup 1.0000x reference)
//
#include <hip/hip_runtime.h>
#include <stdint.h>

// pairs_of_pairs: fused [concat -> conv1x1+relu x3]
// B=32, C=64, S=64, CC=128, OC=256. 2016 rows of 64 positions.
// R19 = R17 (best, 99.6us) + A-IN-REGISTERS. R18's clean A/B-load swap
// (2->4 global A, 8->4 LDS B per kk) cost 38% => kk-loop is bound by the
// dependent GLOBAL weight-load chain, not LDS. Fix: per-wave A-slice
// (32o x 256k = 16 frags = 64 VGPR) batch-loaded once per layer: aload(0)
// under the build's HBM loads, aload(L+1) under h-pack + barriers. kk-loop
// = pure ds_read_b128 + MFMA, aw[mf][kk] statically indexed (rule #20).
// R8 tried this in a 4-wave/1-row shape (1 wave/SIMD -> 176us); here the
// 8-wave/2-row shape keeps 2 waves/SIMD: ~126 VGPR + 64 AGPR < 256 cap.
// Kept from R17: 2 rows/block (b0,b0+16), grid 1008, 512 thr, 8 waves x
// 32o x 128pos, direct build with x-chunk reg-overlap into layer-0 kk0-3,
// X = 64KB 4-chunk swizzled (rolled chunk aliased from chunk2 at shifted
// pos), full kk unroll, direct 64B-segment stores, zero post-layer-2 sync.

typedef __attribute__((ext_vector_type(8))) __bf16 bf16x8;
typedef __attribute__((ext_vector_type(4))) float f32x4;
typedef __attribute__((ext_vector_type(4))) unsigned short u16x4;
typedef __attribute__((ext_vector_type(8))) unsigned short u16x8;

__device__ __forceinline__ unsigned short f2bf(float f) {
  unsigned int u = __builtin_bit_cast(unsigned int, f);
  u += 0x7FFFu + ((u >> 16) & 1u);
  return (unsigned short)(u >> 16);
}

// X: 4 chunk regions of [128 pos][64 ch] bf16 (8192 elems each).
// Within chunk: 16B-slot = pos*8 + ((c6/8) ^ (pos&7)) -> max 2-way (free).
__device__ __forceinline__ int xaddr(int pos, int c) {
  int slot = (pos << 3) + ((((c & 63) >> 3) ^ pos) & 7);
  return ((c >> 6) << 13) + (slot << 3) + (c & 7);
}

__global__ void wconv_kernel(const float* __restrict__ W1, const float* __restrict__ W2,
                             const float* __restrict__ W3, unsigned short* __restrict__ wb) {
  int i = (blockIdx.x * 256 + threadIdx.x) * 4;  // grid 64 -> 65536 per layer
  const float* Ws[3] = {W1, W2, W3};
#pragma unroll
  for (int L = 0; L < 3; ++L) {
    f32x4 a = *(const f32x4*)(Ws[L] + i);
    u16x4 p;
#pragma unroll
    for (int v = 0; v < 4; ++v) p[v] = f2bf(a[v]);
    *(u16x4*)(wb + L * 65536 + i) = p;
  }
}

__global__ __launch_bounds__(512, 1)
void fused_kernel(const float* __restrict__ x, const float* __restrict__ xc,
                  const unsigned short* __restrict__ wb,
                  const float* __restrict__ b1, const float* __restrict__ b2,
                  const float* __restrict__ b3, float* __restrict__ out) {
  __shared__ __align__(16) unsigned char lraw[65536];
  unsigned short* X = (unsigned short*)lraw;   // 64KB, 4 chunk regions

  const int r = blockIdx.x;       // 0..1007
  const int b0 = r / 63;          // 0..15 ; row1 uses b0+16
  const int dd = r % 63;
  const int d = dd + 1;
  const int tid = threadIdx.x;    // 0..511
  const int lane = tid & 63;
  const int g16 = lane >> 4;
  const int l16 = lane & 15;
  const int wv = tid >> 6;        // wave 0..7
  const int ow = wv * 32;

  const int p = tid & 63;         // build: position owned by this thread
  const int c0 = (tid >> 6) << 3; // build: c-octet 0,8,...,56

  // A-in-regs: aw[mf][kk] = 8 bf16 of weight row (ow+mf*16+l16),
  // k = kk*32 + g16*8 .. +8. 16 frags x 4 VGPR = 64 VGPR.
  bf16x8 aw[2][8];
  const unsigned short* wrow = wb + (ow + l16) * 256 + g16 * 8;
  auto aload = [&](int layer) {
    const unsigned short* wl = wrow + layer * 65536;
#pragma unroll
    for (int mf = 0; mf < 2; ++mf)
#pragma unroll
      for (int kk = 0; kk < 8; ++kk)
        aw[mf][kk] = __builtin_bit_cast(
            bf16x8, *(const u16x8*)(wl + mf * 16 * 256 + kk * 32));
  };

  aload(0);  // L2 latency hides under the build's HBM loads below

  // ---- issue x-chunk loads FIRST (latency hidden under build + kk0-3) ----
  float xreg[2][8];
#pragma unroll
  for (int rr = 0; rr < 2; ++rr)
#pragma unroll
    for (int j = 0; j < 8; ++j)
      xreg[rr][j] = x[((b0 + 16 * rr) * 64 + c0 + j) * 64 + p];

  // ---- build chunks 0,1 (xc) for both rows: direct global->LDS ----
#pragma unroll
  for (int cr = 0; cr < 4; ++cr) {
    const int rr = cr >> 1;
    const int ck = cr & 1;
    const int b = b0 + 16 * rr;
    u16x8 v;
#pragma unroll
    for (int j = 0; j < 8; ++j)
      v[j] = f2bf(xc[(((b * 128 + ck * 64 + c0 + j) * 63) + dd) * 64 + p]);
    *(u16x8*)&X[xaddr(rr * 64 + p, ck * 64 + c0)] = v;
  }
  __syncthreads();  // chunks 0,1 ready

  // ---------------- 3 fused conv1x1+relu layers ----------------
  for (int layer = 0; layer < 3; ++layer) {
    const float* bias = (layer == 0) ? b1 : (layer == 1) ? b2 : b3;
    const bool al3 = (layer == 0);     // layer 0: k in [192,256) aliases chunk2 shifted

    f32x4 acc[2][8] = {};              // [mf][nf], wave tile = 32 o x 128 pos

#pragma unroll
    for (int kk = 0; kk < 8; ++kk) {   // FULL unroll; pure ds_read + MFMA
      if (al3 && kk == 4) {
        // write x-chunk (c2) from regs, then barrier; kk0-3 used chunks 0,1 only
#pragma unroll
        for (int rr = 0; rr < 2; ++rr) {
          u16x8 v;
#pragma unroll
          for (int j = 0; j < 8; ++j) v[j] = f2bf(xreg[rr][j]);
          *(u16x8*)&X[xaddr(rr * 64 + p, 128 + c0)] = v;
        }
        __syncthreads();               // c2 ready for kk 4-7
      }
      int kb = kk * 32 + g16 * 8;      // this lane-group's k-base
      bool a3 = al3 && (kk >= 6);
      int cc = a3 ? (128 + (kb & 63)) : kb;  // rolled -> chunk2 region
      bf16x8 bfr[4];
#pragma unroll
      for (int nf = 0; nf < 4; ++nf) { // row0 positions 0..63
        int i = nf * 16 + l16;
        int ie = a3 ? ((i - d) & 63) : i;
        bfr[nf] = __builtin_bit_cast(bf16x8, *(const u16x8*)&X[xaddr(ie, cc)]);
      }
#pragma unroll
      for (int mf = 0; mf < 2; ++mf)
#pragma unroll
        for (int nf = 0; nf < 4; ++nf)
          acc[mf][nf] = __builtin_amdgcn_mfma_f32_16x16x32_bf16(aw[mf][kk], bfr[nf], acc[mf][nf], 0, 0, 0);
#pragma unroll
      for (int nf = 0; nf < 4; ++nf) { // row1 positions 64..127
        int i = nf * 16 + l16;
        int ie = 64 + (a3 ? ((i - d) & 63) : i);
        bfr[nf] = __builtin_bit_cast(bf16x8, *(const u16x8*)&X[xaddr(ie, cc)]);
      }
#pragma unroll
      for (int mf = 0; mf < 2; ++mf)
#pragma unroll
        for (int nf = 0; nf < 4; ++nf)
          acc[mf][4 + nf] = __builtin_amdgcn_mfma_f32_16x16x32_bf16(aw[mf][kk], bfr[nf], acc[mf][4 + nf], 0, 0, 0);
    }

    if (layer < 2) {
      aload(layer + 1);  // next layer's A; latency hides under h-pack + barriers
      __syncthreads();   // all waves done reading X before it is overwritten
      // bias + relu -> bf16 back into X (D frag: pos = l16 col, o = g16*4+v)
#pragma unroll
      for (int mf = 0; mf < 2; ++mf) {
        int o0 = ow + mf * 16 + g16 * 4;
        f32x4 bv = *(const f32x4*)(bias + o0);
#pragma unroll
        for (int nf = 0; nf < 8; ++nf) {
          int pos = nf * 16 + l16;     // 0..127 covers both rows
          u16x4 pk;
#pragma unroll
          for (int v = 0; v < 4; ++v)
            pk[v] = f2bf(fmaxf(acc[mf][nf][v] + bv[v], 0.f));
          *(u16x4*)&X[xaddr(pos, o0)] = pk;
        }
      }
      __syncthreads();
    } else {
      // layer 2: bias+relu -> DIRECT global stores, zero barriers.
      // 16 lanes (l16) write 16 consecutive pos at fixed o -> 64B segments.
#pragma unroll
      for (int rr = 0; rr < 2; ++rr) {
        const int bq = b0 + 16 * rr;
#pragma unroll
        for (int mf = 0; mf < 2; ++mf) {
          int o0 = ow + mf * 16 + g16 * 4;
          f32x4 bv = *(const f32x4*)(bias + o0);
#pragma unroll
          for (int nf = 0; nf < 4; ++nf) {
            int pos = nf * 16 + l16;   // within-row position
#pragma unroll
            for (int v = 0; v < 4; ++v)
              out[(((bq * 256 + o0 + v) * 63) + dd) * 64 + pos] =
                  fmaxf(acc[mf][rr * 4 + nf][v] + bv[v], 0.f);
          }
        }
      }
    }
  }
}

extern "C" void kernel_launch(void* const* d_in, const int* in_sizes, int n_in,
                              void* d_out, int out_size, void* d_ws, size_t ws_size,
                              hipStream_t stream) {
  const float* x  = (const float*)d_in[0];
  const float* xc = (const float*)d_in[1];
  const float* W1 = (const float*)d_in[2];
  const float* b1 = (const float*)d_in[3];
  const float* W2 = (const float*)d_in[4];
  const float* b2 = (const float*)d_in[5];
  const float* W3 = (const float*)d_in[6];
  const float* b3 = (const float*)d_in[7];
  float* out = (float*)d_out;
  unsigned short* wb = (unsigned short*)d_ws;  // 3 x 256 x 256 bf16 = 384 KB

  wconv_kernel<<<64, 256, 0, stream>>>(W1, W2, W3, wb);
  fused_kernel<<<1008, 512, 0, stream>>>(x, xc, wb, b1, b2, b3, out);
}

// Round 21
// 96.769 us; speedup vs baseline: 1.4983x; 1.4983x over previous
//
#include <hip/hip_runtime.h>
#include <stdint.h>

// pairs_of_pairs: fused [concat -> conv1x1+relu x3]
// B=32, C=64, S=64, CC=128, OC=256. 2016 rows of 64 positions.
// R20 = R17 (best, 99.6us) + PING-PONG h BUFFERS (LDS 128KB = 2 x 64KB).
// R19 lesson: 512-thr kernels are compiler-pinned at 128 VGPR -> A-in-regs
// impossible. R17's remaining inefficiency: barrier-lockstep keeps all waves
// in the SAME phase (homogeneous stalls, pipes ~40% overlapped). Layer L now
// reads buf[L parity] and writes h to the OTHER buffer: the read/overwrite
// hazard barrier vanishes (6 -> 4 barriers) and a wave's h-pack VALU runs
// immediately after its own kk-loop, overlapping slower waves' MFMA
// (heterogeneous phases; m114 MFMA||VALU concurrency finally engages).
// Occupancy unchanged (1 block/CU before and after). Registers unchanged.
// Schedule: build->bufA(c01) |bar| L0: read bufA (c2 @kk4 |bar|), h1->bufB
// |bar| L1: read bufB, h2->bufA |bar| L2: read bufA -> direct stores, exit.
// Kept from R17: 2 rows/block (b0,b0+16), grid 1008, 512 thr, 8 waves x
// 32o x 128pos, xaddr 4-chunk swizzle (rolled chunk aliased from chunk2 at
// shifted pos), full kk unroll, direct 64B-segment stores, (512,1).

typedef __attribute__((ext_vector_type(8))) __bf16 bf16x8;
typedef __attribute__((ext_vector_type(4))) float f32x4;
typedef __attribute__((ext_vector_type(4))) unsigned short u16x4;
typedef __attribute__((ext_vector_type(8))) unsigned short u16x8;

__device__ __forceinline__ unsigned short f2bf(float f) {
  unsigned int u = __builtin_bit_cast(unsigned int, f);
  u += 0x7FFFu + ((u >> 16) & 1u);
  return (unsigned short)(u >> 16);
}

// 64KB buffer layout: 4 chunk regions of [128 pos][64 ch] bf16 (8192 each).
// Within chunk: 16B-slot = pos*8 + ((c6/8) ^ (pos&7)) -> max 2-way (free).
__device__ __forceinline__ int xaddr(int pos, int c) {
  int slot = (pos << 3) + ((((c & 63) >> 3) ^ pos) & 7);
  return ((c >> 6) << 13) + (slot << 3) + (c & 7);
}

__global__ void wconv_kernel(const float* __restrict__ W1, const float* __restrict__ W2,
                             const float* __restrict__ W3, unsigned short* __restrict__ wb) {
  int i = (blockIdx.x * 256 + threadIdx.x) * 4;  // grid 64 -> 65536 per layer
  const float* Ws[3] = {W1, W2, W3};
#pragma unroll
  for (int L = 0; L < 3; ++L) {
    f32x4 a = *(const f32x4*)(Ws[L] + i);
    u16x4 p;
#pragma unroll
    for (int v = 0; v < 4; ++v) p[v] = f2bf(a[v]);
    *(u16x4*)(wb + L * 65536 + i) = p;
  }
}

__global__ __launch_bounds__(512, 1)
void fused_kernel(const float* __restrict__ x, const float* __restrict__ xc,
                  const unsigned short* __restrict__ wb,
                  const float* __restrict__ b1, const float* __restrict__ b2,
                  const float* __restrict__ b3, float* __restrict__ out) {
  __shared__ __align__(16) unsigned char lraw[131072];   // bufA 64KB | bufB 64KB
  unsigned short* bufA = (unsigned short*)lraw;
  unsigned short* bufB = (unsigned short*)(lraw + 65536);

  const int r = blockIdx.x;       // 0..1007
  const int b0 = r / 63;          // 0..15 ; row1 uses b0+16
  const int dd = r % 63;
  const int d = dd + 1;
  const int tid = threadIdx.x;    // 0..511
  const int lane = tid & 63;
  const int g16 = lane >> 4;
  const int l16 = lane & 15;
  const int wv = tid >> 6;        // wave 0..7
  const int ow = wv * 32;

  const int p = tid & 63;         // build: position owned by this thread
  const int c0 = (tid >> 6) << 3; // build: c-octet 0,8,...,56

  // ---- issue x-chunk loads FIRST (latency hidden under build + kk0-3) ----
  float xreg[2][8];
#pragma unroll
  for (int rr = 0; rr < 2; ++rr)
#pragma unroll
    for (int j = 0; j < 8; ++j)
      xreg[rr][j] = x[((b0 + 16 * rr) * 64 + c0 + j) * 64 + p];

  // ---- build chunks 0,1 (xc) for both rows into bufA ----
#pragma unroll
  for (int cr = 0; cr < 4; ++cr) {
    const int rr = cr >> 1;
    const int ck = cr & 1;
    const int b = b0 + 16 * rr;
    u16x8 v;
#pragma unroll
    for (int j = 0; j < 8; ++j)
      v[j] = f2bf(xc[(((b * 128 + ck * 64 + c0 + j) * 63) + dd) * 64 + p]);
    *(u16x8*)&bufA[xaddr(rr * 64 + p, ck * 64 + c0)] = v;
  }
  __syncthreads();  // bar 1: chunks 0,1 ready

  // ---------------- 3 fused conv1x1+relu layers ----------------
  for (int layer = 0; layer < 3; ++layer) {
    const unsigned short* wl = wb + layer * 65536;
    const float* bias = (layer == 0) ? b1 : (layer == 1) ? b2 : b3;
    const bool al3 = (layer == 0);     // layer 0: k in [192,256) aliases chunk2 shifted
    // ping-pong: L0 reads bufA, writes bufB; L1 reads bufB, writes bufA;
    // L2 reads bufA, stores to global.
    unsigned short* Xr = (layer == 1) ? bufB : bufA;
    unsigned short* Xw = (layer == 0) ? bufB : bufA;

    f32x4 acc[2][8] = {};              // [mf][nf], wave tile = 32 o x 128 pos

#pragma unroll
    for (int kk = 0; kk < 8; ++kk) {   // FULL unroll; branches fold
      if (al3 && kk == 4) {
        // write x-chunk (c2) from regs into bufA, then barrier (bar 2)
#pragma unroll
        for (int rr = 0; rr < 2; ++rr) {
          u16x8 v;
#pragma unroll
          for (int j = 0; j < 8; ++j) v[j] = f2bf(xreg[rr][j]);
          *(u16x8*)&bufA[xaddr(rr * 64 + p, 128 + c0)] = v;
        }
        __syncthreads();               // c2 ready for kk 4-7
      }
      int kb = kk * 32 + g16 * 8;      // this lane-group's k-base
      bool a3 = al3 && (kk >= 6);
      int cc = a3 ? (128 + (kb & 63)) : kb;  // rolled -> chunk2 region
      bf16x8 afr[2];
#pragma unroll
      for (int mf = 0; mf < 2; ++mf)
        afr[mf] = __builtin_bit_cast(
            bf16x8, *(const u16x8*)(wl + (ow + mf * 16 + l16) * 256 + kb));
      bf16x8 bfr[4];
#pragma unroll
      for (int nf = 0; nf < 4; ++nf) { // row0 positions 0..63
        int i = nf * 16 + l16;
        int ie = a3 ? ((i - d) & 63) : i;
        bfr[nf] = __builtin_bit_cast(bf16x8, *(const u16x8*)&Xr[xaddr(ie, cc)]);
      }
#pragma unroll
      for (int mf = 0; mf < 2; ++mf)
#pragma unroll
        for (int nf = 0; nf < 4; ++nf)
          acc[mf][nf] = __builtin_amdgcn_mfma_f32_16x16x32_bf16(afr[mf], bfr[nf], acc[mf][nf], 0, 0, 0);
#pragma unroll
      for (int nf = 0; nf < 4; ++nf) { // row1 positions 64..127
        int i = nf * 16 + l16;
        int ie = 64 + (a3 ? ((i - d) & 63) : i);
        bfr[nf] = __builtin_bit_cast(bf16x8, *(const u16x8*)&Xr[xaddr(ie, cc)]);
      }
#pragma unroll
      for (int mf = 0; mf < 2; ++mf)
#pragma unroll
        for (int nf = 0; nf < 4; ++nf)
          acc[mf][4 + nf] = __builtin_amdgcn_mfma_f32_16x16x32_bf16(afr[mf], bfr[nf], acc[mf][4 + nf], 0, 0, 0);
    }

    if (layer < 2) {
      // NO pre-barrier: h goes to the OTHER buffer. Wave packs immediately
      // after its own kk-loop -> overlaps slower waves' MFMA.
#pragma unroll
      for (int mf = 0; mf < 2; ++mf) {
        int o0 = ow + mf * 16 + g16 * 4;
        f32x4 bv = *(const f32x4*)(bias + o0);
#pragma unroll
        for (int nf = 0; nf < 8; ++nf) {
          int pos = nf * 16 + l16;     // 0..127 covers both rows
          u16x4 pk;
#pragma unroll
          for (int v = 0; v < 4; ++v)
            pk[v] = f2bf(fmaxf(acc[mf][nf][v] + bv[v], 0.f));
          *(u16x4*)&Xw[xaddr(pos, o0)] = pk;
        }
      }
      __syncthreads();  // bar: h complete before next layer reads it
    } else {
      // layer 2: bias+relu -> DIRECT global stores, zero barriers.
      // 16 lanes (l16) write 16 consecutive pos at fixed o -> 64B segments.
#pragma unroll
      for (int rr = 0; rr < 2; ++rr) {
        const int bq = b0 + 16 * rr;
#pragma unroll
        for (int mf = 0; mf < 2; ++mf) {
          int o0 = ow + mf * 16 + g16 * 4;
          f32x4 bv = *(const f32x4*)(bias + o0);
#pragma unroll
          for (int nf = 0; nf < 4; ++nf) {
            int pos = nf * 16 + l16;   // within-row position
#pragma unroll
            for (int v = 0; v < 4; ++v)
              out[(((bq * 256 + o0 + v) * 63) + dd) * 64 + pos] =
                  fmaxf(acc[mf][rr * 4 + nf][v] + bv[v], 0.f);
          }
        }
      }
    }
  }
}

extern "C" void kernel_launch(void* const* d_in, const int* in_sizes, int n_in,
                              void* d_out, int out_size, void* d_ws, size_t ws_size,
                              hipStream_t stream) {
  const float* x  = (const float*)d_in[0];
  const float* xc = (const float*)d_in[1];
  const float* W1 = (const float*)d_in[2];
  const float* b1 = (const float*)d_in[3];
  const float* W2 = (const float*)d_in[4];
  const float* b2 = (const float*)d_in[5];
  const float* W3 = (const float*)d_in[6];
  const float* b3 = (const float*)d_in[7];
  float* out = (float*)d_out;
  unsigned short* wb = (unsigned short*)d_ws;  // 3 x 256 x 256 bf16 = 384 KB

  wconv_kernel<<<64, 256, 0, stream>>>(W1, W2, W3, wb);
  fused_kernel<<<1008, 512, 0, stream>>>(x, xc, wb, b1, b2, b3, out);
}

// Round 22
// 91.847 us; speedup vs baseline: 1.5786x; 1.0536x over previous
//
#include <hip/hip_runtime.h>
#include <stdint.h>

// pairs_of_pairs: fused [concat -> conv1x1+relu x3]
// B=32, C=64, S=64, CC=128, OC=256. 2016 rows of 64 positions.
// R21 = R20 (best, 96.8us) + {kk4-barrier removal, v_cvt_pk_bf16_f32 packing}.
// (1) c2 written at END of build (xreg issues first; latency covered by the
//     xc loads behind it) -> layer-0 kk runs uninterrupted, barriers 4 -> 3
//     (minimum for 3 dependent layers).
// (2) all fp32->bf16 conversion via v_cvt_pk_bf16_f32 inline asm (2 vals/op,
//     no builtin on gfx950): build 48->24 ops/thread, h-pack 64->32/wave.
//     VALUBusy was 21% - 2nd largest pipe.
// Kept from R20: ping-pong h buffers (LDS 128KB: L0 reads bufA -> h1 to bufB
// -> L1 reads bufB -> h2 to bufA -> L2 reads bufA -> direct stores, exit),
// 2 rows/block (b0,b0+16), grid 1008, 512 thr, 8 waves x 32o x 128pos,
// xaddr 4-chunk swizzle, rolled chunk aliased from chunk2 at shifted pos,
// full kk unroll, direct 64B-segment stores, launch_bounds(512,1).

typedef __attribute__((ext_vector_type(8))) __bf16 bf16x8;
typedef __attribute__((ext_vector_type(4))) float f32x4;
typedef __attribute__((ext_vector_type(4))) unsigned short u16x4;
typedef __attribute__((ext_vector_type(8))) unsigned short u16x8;
typedef __attribute__((ext_vector_type(2))) unsigned int u32x2;
typedef __attribute__((ext_vector_type(4))) unsigned int u32x4;

__device__ __forceinline__ unsigned short f2bf(float f) {
  unsigned int u = __builtin_bit_cast(unsigned int, f);
  u += 0x7FFFu + ((u >> 16) & 1u);
  return (unsigned short)(u >> 16);
}

// packed fp32x2 -> bf16x2 (RTNE); lo = a, hi = b. No builtin on gfx950 (T12).
__device__ __forceinline__ unsigned int cvtpk(float a, float b) {
  unsigned int r;
  asm("v_cvt_pk_bf16_f32 %0, %1, %2" : "=v"(r) : "v"(a), "v"(b));
  return r;
}

// 64KB buffer layout: 4 chunk regions of [128 pos][64 ch] bf16 (8192 each).
// Within chunk: 16B-slot = pos*8 + ((c6/8) ^ (pos&7)) -> max 2-way (free).
__device__ __forceinline__ int xaddr(int pos, int c) {
  int slot = (pos << 3) + ((((c & 63) >> 3) ^ pos) & 7);
  return ((c >> 6) << 13) + (slot << 3) + (c & 7);
}

__global__ void wconv_kernel(const float* __restrict__ W1, const float* __restrict__ W2,
                             const float* __restrict__ W3, unsigned short* __restrict__ wb) {
  int i = (blockIdx.x * 256 + threadIdx.x) * 4;  // grid 64 -> 65536 per layer
  const float* Ws[3] = {W1, W2, W3};
#pragma unroll
  for (int L = 0; L < 3; ++L) {
    f32x4 a = *(const f32x4*)(Ws[L] + i);
    u16x4 p;
#pragma unroll
    for (int v = 0; v < 4; ++v) p[v] = f2bf(a[v]);
    *(u16x4*)(wb + L * 65536 + i) = p;
  }
}

__global__ __launch_bounds__(512, 1)
void fused_kernel(const float* __restrict__ x, const float* __restrict__ xc,
                  const unsigned short* __restrict__ wb,
                  const float* __restrict__ b1, const float* __restrict__ b2,
                  const float* __restrict__ b3, float* __restrict__ out) {
  __shared__ __align__(16) unsigned char lraw[131072];   // bufA 64KB | bufB 64KB
  unsigned short* bufA = (unsigned short*)lraw;
  unsigned short* bufB = (unsigned short*)(lraw + 65536);

  const int r = blockIdx.x;       // 0..1007
  const int b0 = r / 63;          // 0..15 ; row1 uses b0+16
  const int dd = r % 63;
  const int d = dd + 1;
  const int tid = threadIdx.x;    // 0..511
  const int lane = tid & 63;
  const int g16 = lane >> 4;
  const int l16 = lane & 15;
  const int wv = tid >> 6;        // wave 0..7
  const int ow = wv * 32;

  const int p = tid & 63;         // build: position owned by this thread
  const int c0 = (tid >> 6) << 3; // build: c-octet 0,8,...,56

  // ---- issue x-chunk loads FIRST (latency covered by the xc loads below) --
  float xreg[2][8];
#pragma unroll
  for (int rr = 0; rr < 2; ++rr)
#pragma unroll
    for (int j = 0; j < 8; ++j)
      xreg[rr][j] = x[((b0 + 16 * rr) * 64 + c0 + j) * 64 + p];

  // ---- build chunks 0,1 (xc) for both rows into bufA ----
#pragma unroll
  for (int cr = 0; cr < 4; ++cr) {
    const int rr = cr >> 1;
    const int ck = cr & 1;
    const int b = b0 + 16 * rr;
    float f[8];
#pragma unroll
    for (int j = 0; j < 8; ++j)
      f[j] = xc[(((b * 128 + ck * 64 + c0 + j) * 63) + dd) * 64 + p];
    u32x4 v;
#pragma unroll
    for (int j = 0; j < 4; ++j) v[j] = cvtpk(f[2 * j], f[2 * j + 1]);
    *(u32x4*)&bufA[xaddr(rr * 64 + p, ck * 64 + c0)] = v;
  }
  // ---- chunk 2 (x) from regs: xreg completed long ago; no extra barrier ---
#pragma unroll
  for (int rr = 0; rr < 2; ++rr) {
    u32x4 v;
#pragma unroll
    for (int j = 0; j < 4; ++j) v[j] = cvtpk(xreg[rr][2 * j], xreg[rr][2 * j + 1]);
    *(u32x4*)&bufA[xaddr(rr * 64 + p, 128 + c0)] = v;
  }
  __syncthreads();  // bar 1 of 3: full layer-0 input ready

  // ---------------- 3 fused conv1x1+relu layers ----------------
  for (int layer = 0; layer < 3; ++layer) {
    const unsigned short* wl = wb + layer * 65536;
    const float* bias = (layer == 0) ? b1 : (layer == 1) ? b2 : b3;
    const bool al3 = (layer == 0);     // layer 0: k in [192,256) aliases chunk2 shifted
    // ping-pong: L0 reads bufA, writes bufB; L1 reads bufB, writes bufA;
    // L2 reads bufA, stores to global.
    unsigned short* Xr = (layer == 1) ? bufB : bufA;
    unsigned short* Xw = (layer == 0) ? bufB : bufA;

    f32x4 acc[2][8] = {};              // [mf][nf], wave tile = 32 o x 128 pos

#pragma unroll
    for (int kk = 0; kk < 8; ++kk) {   // FULL unroll, uninterrupted
      int kb = kk * 32 + g16 * 8;      // this lane-group's k-base
      bool a3 = al3 && (kk >= 6);
      int cc = a3 ? (128 + (kb & 63)) : kb;  // rolled -> chunk2 region
      bf16x8 afr[2];
#pragma unroll
      for (int mf = 0; mf < 2; ++mf)
        afr[mf] = __builtin_bit_cast(
            bf16x8, *(const u16x8*)(wl + (ow + mf * 16 + l16) * 256 + kb));
      bf16x8 bfr[4];
#pragma unroll
      for (int nf = 0; nf < 4; ++nf) { // row0 positions 0..63
        int i = nf * 16 + l16;
        int ie = a3 ? ((i - d) & 63) : i;
        bfr[nf] = __builtin_bit_cast(bf16x8, *(const u16x8*)&Xr[xaddr(ie, cc)]);
      }
#pragma unroll
      for (int mf = 0; mf < 2; ++mf)
#pragma unroll
        for (int nf = 0; nf < 4; ++nf)
          acc[mf][nf] = __builtin_amdgcn_mfma_f32_16x16x32_bf16(afr[mf], bfr[nf], acc[mf][nf], 0, 0, 0);
#pragma unroll
      for (int nf = 0; nf < 4; ++nf) { // row1 positions 64..127
        int i = nf * 16 + l16;
        int ie = 64 + (a3 ? ((i - d) & 63) : i);
        bfr[nf] = __builtin_bit_cast(bf16x8, *(const u16x8*)&Xr[xaddr(ie, cc)]);
      }
#pragma unroll
      for (int mf = 0; mf < 2; ++mf)
#pragma unroll
        for (int nf = 0; nf < 4; ++nf)
          acc[mf][4 + nf] = __builtin_amdgcn_mfma_f32_16x16x32_bf16(afr[mf], bfr[nf], acc[mf][4 + nf], 0, 0, 0);
    }

    if (layer < 2) {
      // NO pre-barrier (other buffer). Pack overlaps slower waves' MFMA.
#pragma unroll
      for (int mf = 0; mf < 2; ++mf) {
        int o0 = ow + mf * 16 + g16 * 4;
        f32x4 bv = *(const f32x4*)(bias + o0);
#pragma unroll
        for (int nf = 0; nf < 8; ++nf) {
          int pos = nf * 16 + l16;     // 0..127 covers both rows
          float v0 = fmaxf(acc[mf][nf][0] + bv[0], 0.f);
          float v1 = fmaxf(acc[mf][nf][1] + bv[1], 0.f);
          float v2 = fmaxf(acc[mf][nf][2] + bv[2], 0.f);
          float v3 = fmaxf(acc[mf][nf][3] + bv[3], 0.f);
          u32x2 pk;
          pk[0] = cvtpk(v0, v1);
          pk[1] = cvtpk(v2, v3);
          *(u32x2*)&Xw[xaddr(pos, o0)] = pk;
        }
      }
      __syncthreads();  // bar 2/3: h complete before next layer reads it
    } else {
      // layer 2: bias+relu -> DIRECT global stores, zero barriers.
      // 16 lanes (l16) write 16 consecutive pos at fixed o -> 64B segments.
#pragma unroll
      for (int rr = 0; rr < 2; ++rr) {
        const int bq = b0 + 16 * rr;
#pragma unroll
        for (int mf = 0; mf < 2; ++mf) {
          int o0 = ow + mf * 16 + g16 * 4;
          f32x4 bv = *(const f32x4*)(bias + o0);
#pragma unroll
          for (int nf = 0; nf < 4; ++nf) {
            int pos = nf * 16 + l16;   // within-row position
#pragma unroll
            for (int v = 0; v < 4; ++v)
              out[(((bq * 256 + o0 + v) * 63) + dd) * 64 + pos] =
                  fmaxf(acc[mf][rr * 4 + nf][v] + bv[v], 0.f);
          }
        }
      }
    }
  }
}

extern "C" void kernel_launch(void* const* d_in, const int* in_sizes, int n_in,
                              void* d_out, int out_size, void* d_ws, size_t ws_size,
                              hipStream_t stream) {
  const float* x  = (const float*)d_in[0];
  const float* xc = (const float*)d_in[1];
  const float* W1 = (const float*)d_in[2];
  const float* b1 = (const float*)d_in[3];
  const float* W2 = (const float*)d_in[4];
  const float* b2 = (const float*)d_in[5];
  const float* W3 = (const float*)d_in[6];
  const float* b3 = (const float*)d_in[7];
  float* out = (float*)d_out;
  unsigned short* wb = (unsigned short*)d_ws;  // 3 x 256 x 256 bf16 = 384 KB

  wconv_kernel<<<64, 256, 0, stream>>>(W1, W2, W3, wb);
  fused_kernel<<<1008, 512, 0, stream>>>(x, xc, wb, b1, b2, b3, out);
}